// Round 11
// baseline (264.644 us; speedup 1.0000x reference)
//
#include <hip/hip_runtime.h>
#include <hip/hip_bf16.h>

#define N_B   16
#define CIO   512
#define LSEQ  384
#define DH    64
#define NH    8
#define CHID  512
#define ME    384

typedef __hip_bfloat16 bf16;
typedef __attribute__((ext_vector_type(8))) short bf16x8;
typedef __attribute__((ext_vector_type(4))) float f32x4;

__device__ __forceinline__ unsigned short f2bs(float f) {
    union { bf16 b; unsigned short u; } cv; cv.b = __float2bfloat16(f); return cv.u;
}

// ---------------------------------------------------------------------------
// prep (+ folded wconv): X1/X0 rezero -> bf16 transposed [n][l][c]; gate
// partials into gpart; first 512 flat-id blocks also convert one 2048-elem
// weight chunk fp32->bf16.
// ---------------------------------------------------------------------------
__launch_bounds__(256)
__global__ void prep_kernel(const float* __restrict__ x, const float* __restrict__ xorg,
                            const float* __restrict__ abspos,
                            const float* __restrict__ qkorg, const float* __restrict__ qkpos,
                            const float* __restrict__ vorg,
                            const float* __restrict__ gw,
                            const float* __restrict__ q_w, const float* __restrict__ k_w,
                            const float* __restrict__ v_w, const float* __restrict__ dense_w,
                            bf16* __restrict__ wqb, bf16* __restrict__ wkb,
                            bf16* __restrict__ wvb, bf16* __restrict__ wdb,
                            bf16* __restrict__ x1t, bf16* __restrict__ x0t,
                            float* __restrict__ gpart)
{
    __shared__ bf16 T1[64 * 72], T0[64 * 72];   // [l][c], rows padded to 72
    __shared__ float Traw[64 * 65];             // [c][l] fp32, stride 65
    __shared__ float gws[NH * 64];
    __shared__ float r0[64], r1[64], r2[64];
    const int tid = threadIdx.x;
    const int cb = blockIdx.x;
    const int c0 = cb * 64;
    const int l0 = blockIdx.y * 64;
    const int n  = blockIdx.z;

    // folded wconv
    {
        int f = blockIdx.x + 8 * (blockIdx.y + 6 * blockIdx.z);
        if (f < 512) {
            int e = (f * 256 + tid) * 8;
            int which = e >> 18;
            int off = e & ((1 << 18) - 1);
            const float* s = which == 0 ? q_w : which == 1 ? k_w : which == 2 ? v_w : dense_w;
            bf16* d       = which == 0 ? wqb : which == 1 ? wkb : which == 2 ? wvb : wdb;
            float4 f0 = *(const float4*)&s[off];
            float4 f1 = *(const float4*)&s[off + 4];
            unsigned short u[8] = {f2bs(f0.x), f2bs(f0.y), f2bs(f0.z), f2bs(f0.w),
                                   f2bs(f1.x), f2bs(f1.y), f2bs(f1.z), f2bs(f1.w)};
            *(uint4*)&d[off] = *(uint4*)u;
        }
    }

    if (tid < 64) {
        int gidx = (c0 + tid) >> 3;
        r0[tid] = vorg[gidx];
        r1[tid] = qkorg[gidx];
        r2[tid] = qkpos[gidx];
    }
    for (int t = tid; t < NH * 64; t += 256) {
        int h = t >> 6, c = t & 63;
        gws[t] = gw[h * CIO + c0 + c];
    }
    __syncthreads();
    const int l = tid & 63, cs = tid >> 6;
    #pragma unroll
    for (int r = 0; r < 16; r++) {
        int cl = r * 4 + cs;
        size_t gi = ((size_t)n * CIO + c0 + cl) * LSEQ + l0 + l;
        float xv = x[gi], xo = xorg[gi];
        Traw[cl * 65 + l] = xv;
        T0[l * 72 + cl] = __float2bfloat16(xv + r0[cl] * xo);
        T1[l * 72 + cl] = __float2bfloat16(xv + r1[cl] * xo + r2[cl] * abspos[gi]);
    }
    __syncthreads();
    for (int t = tid; t < NH * 64; t += 256) {
        int h = t >> 6, ll = t & 63;
        float s = 0.f;
        #pragma unroll
        for (int c = 0; c < 64; c++) s += gws[h * 64 + c] * Traw[c * 65 + ll];
        gpart[(((size_t)cb * N_B + n) * NH + h) * LSEQ + l0 + ll] = s;
    }
    #pragma unroll
    for (int t = 0; t < 2; t++) {
        int idx = t * 256 + tid;
        int lr = idx >> 3, u = idx & 7;
        size_t go = ((size_t)n * LSEQ + l0 + lr) * CIO + c0 + u * 8;
        *(uint4*)&x1t[go] = *(const uint4*)&T1[lr * 72 + u * 8];
        *(uint4*)&x0t[go] = *(const uint4*)&T0[lr * 72 + u * 8];
    }
}

// ---------------------------------------------------------------------------
// qkv GEMM, 64x64 tiles for high occupancy (9KB LDS, ~20 waves/CU).
// 1536 blocks: kind 0 = fused q+k (shared B=x1t), kind 1 = v. n = Bid&7 (+8).
// ---------------------------------------------------------------------------
__launch_bounds__(256, 5)
__global__ void qkv_kernel(const bf16* __restrict__ wq, const bf16* __restrict__ wk,
                           const bf16* __restrict__ wv,
                           const bf16* __restrict__ x1t, const bf16* __restrict__ x0t,
                           bf16* __restrict__ qb, bf16* __restrict__ kb,
                           bf16* __restrict__ vb)
{
    __shared__ __align__(16) bf16 S[64 * 72];   // 9216 B
    const int tid = threadIdx.x;
    const int lane = tid & 63, w = tid >> 6;
    const int l15 = lane & 15, g = lane >> 4;
    const int Bid = blockIdx.x;
    const int rres = Bid & 7, qq = Bid >> 3;    // 0..191
    const int n = rres + 8 * (qq / 96);
    const int t = qq % 96;
    const int kind = t / 48;                    // 0 = qk, 1 = v
    const int tt = t % 48;
    const int o0 = (tt / 6) * 64;
    const int l0 = (tt % 6) * 64;

    const bf16* brow = (kind ? x0t : x1t) +
        ((size_t)n * LSEQ + l0 + w * 16 + l15) * CIO + 8 * g;

    if (kind == 0) {
        const bf16* aqrow = wq + (size_t)(o0 + l15) * CIO + 8 * g;
        const bf16* akrow = wk + (size_t)(o0 + l15) * CIO + 8 * g;
        f32x4 accq[4], acck[4];
        #pragma unroll
        for (int mt = 0; mt < 4; mt++) {
            accq[mt] = f32x4{0.f, 0.f, 0.f, 0.f};
            acck[mt] = f32x4{0.f, 0.f, 0.f, 0.f};
        }
        #pragma unroll 4
        for (int it = 0; it < 16; it++) {
            const int k0 = it * 32;
            bf16x8 b = *(const bf16x8*)&brow[k0];
            bf16x8 aq[4], ak[4];
            #pragma unroll
            for (int mt = 0; mt < 4; mt++) {
                aq[mt] = *(const bf16x8*)&aqrow[(size_t)mt * 16 * CIO + k0];
                ak[mt] = *(const bf16x8*)&akrow[(size_t)mt * 16 * CIO + k0];
            }
            #pragma unroll
            for (int mt = 0; mt < 4; mt++) {
                accq[mt] = __builtin_amdgcn_mfma_f32_16x16x32_bf16(aq[mt], b, accq[mt], 0, 0, 0);
                acck[mt] = __builtin_amdgcn_mfma_f32_16x16x32_bf16(ak[mt], b, acck[mt], 0, 0, 0);
            }
        }
        // q epilogue: S[l][d] stride 72, then coalesced 16B stores
        const int h = o0 >> 6;
        bf16* qg = qb + ((size_t)n * NH + h) * LSEQ * DH + (size_t)l0 * DH;
        bf16* kg = kb + ((size_t)n * NH + h) * LSEQ * DH + (size_t)l0 * DH;
        #pragma unroll
        for (int mt = 0; mt < 4; mt++)
            #pragma unroll
            for (int r = 0; r < 4; r++)
                S[(w * 16 + l15) * 72 + mt * 16 + 4 * g + r] = __float2bfloat16(accq[mt][r]);
        __syncthreads();
        #pragma unroll
        for (int t2 = 0; t2 < 2; t2++) {
            int idx = t2 * 256 + tid;
            int lr = idx >> 3, u = idx & 7;
            *(uint4*)&qg[(size_t)lr * DH + u * 8] = *(const uint4*)&S[lr * 72 + u * 8];
        }
        __syncthreads();
        #pragma unroll
        for (int mt = 0; mt < 4; mt++)
            #pragma unroll
            for (int r = 0; r < 4; r++)
                S[(w * 16 + l15) * 72 + mt * 16 + 4 * g + r] = __float2bfloat16(acck[mt][r]);
        __syncthreads();
        #pragma unroll
        for (int t2 = 0; t2 < 2; t2++) {
            int idx = t2 * 256 + tid;
            int lr = idx >> 3, u = idx & 7;
            *(uint4*)&kg[(size_t)lr * DH + u * 8] = *(const uint4*)&S[lr * 72 + u * 8];
        }
    } else {
        const bf16* arow = wv + (size_t)(o0 + l15) * CIO + 8 * g;
        f32x4 acc[4];
        #pragma unroll
        for (int mt = 0; mt < 4; mt++) acc[mt] = f32x4{0.f, 0.f, 0.f, 0.f};
        #pragma unroll 4
        for (int it = 0; it < 16; it++) {
            const int k0 = it * 32;
            bf16x8 b = *(const bf16x8*)&brow[k0];
            bf16x8 a[4];
            #pragma unroll
            for (int mt = 0; mt < 4; mt++)
                a[mt] = *(const bf16x8*)&arow[(size_t)mt * 16 * CIO + k0];
            #pragma unroll
            for (int mt = 0; mt < 4; mt++)
                acc[mt] = __builtin_amdgcn_mfma_f32_16x16x32_bf16(a[mt], b, acc[mt], 0, 0, 0);
        }
        // v epilogue: S[o][l] stride 72, natural [n][o][l] stores
        #pragma unroll
        for (int mt = 0; mt < 4; mt++)
            #pragma unroll
            for (int r = 0; r < 4; r++)
                S[(mt * 16 + 4 * g + r) * 72 + w * 16 + l15] = __float2bfloat16(acc[mt][r]);
        __syncthreads();
        bf16* og = vb + ((size_t)n * CHID + o0) * LSEQ + l0;
        #pragma unroll
        for (int t2 = 0; t2 < 2; t2++) {
            int idx = t2 * 256 + tid;
            int orow = idx >> 3, u = idx & 7;
            *(uint4*)&og[(size_t)orow * LSEQ + u * 8] = *(const uint4*)&S[orow * 72 + u * 8];
        }
    }
}

// ---------------------------------------------------------------------------
// MFMA attention: 768 blocks, n = Bid&7 (+8). Direct-global K B-frags,
// two-pass PV through P[64][200] (30KB LDS -> 3 blocks/CU), V prefetch.
// ---------------------------------------------------------------------------
__launch_bounds__(256, 3)
__global__ void attn_kernel(const bf16* __restrict__ qt,   // [n][h][i][d]
                            const bf16* __restrict__ kt,   // [n][h][j][d]
                            const bf16* __restrict__ v,    // [n][h*64+d][j]
                            const float* __restrict__ gpart,
                            const float* __restrict__ gb,
                            const float* __restrict__ mask,
                            const float* __restrict__ norm,
                            const float* __restrict__ relpos,
                            bf16* __restrict__ ctxt)
{
    __shared__ __align__(16) char smem[25600];   // P[64][200] bf16 | O[64][72]
    __shared__ float relp_s[2 * ME - 1];
    __shared__ float radd_s[LSEQ];

    bf16* P = (bf16*)smem;
    bf16* O = (bf16*)smem;

    const int tid = threadIdx.x;
    const int Bid = blockIdx.x;
    const int rres = Bid & 7, qq = Bid >> 3;   // qq 0..95
    const int n = rres + 8 * (qq / 48);
    const int rem = qq % 48;
    const int h = rem / 6;
    const int i0 = (rem % 6) * 64;
    const int lane = tid & 63;
    const int w = tid >> 6;
    const int l15 = lane & 15, g = lane >> 4;
    const int m0 = w * 16;

    const size_t nh = (size_t)n * NH + h;
    const bf16* kt_g = kt + nh * LSEQ * DH;
    const bf16* vg   = v + ((size_t)n * CHID + h * DH) * LSEQ;

    {
        const float gbh = gb[h];
        for (int i = tid; i < LSEQ; i += 256) {
            float s = gbh + mask[(size_t)n * LSEQ + i];
            #pragma unroll
            for (int cb = 0; cb < 8; cb++)
                s += gpart[(((size_t)cb * N_B + n) * NH + h) * LSEQ + i];
            radd_s[i] = s;
        }
    }
    for (int i = tid; i < 2 * ME - 1; i += 256) relp_s[i] = relpos[i];

    const bf16* qrow = qt + (nh * LSEQ + i0 + m0 + l15) * DH;
    bf16x8 a0 = *(const bf16x8*)&qrow[8 * g];
    bf16x8 a1 = *(const bf16x8*)&qrow[8 * g + 32];
    const float inv_norm = 1.0f / norm[n];
    __syncthreads();

    // S = Q K^T
    f32x4 acc[24];
    #pragma unroll
    for (int jt = 0; jt < 24; jt++) acc[jt] = f32x4{0.f, 0.f, 0.f, 0.f};
    #pragma unroll
    for (int jt = 0; jt < 24; jt++) {
        const bf16* kr = &kt_g[(size_t)(jt * 16 + l15) * DH + 8 * g];
        bf16x8 b0 = *(const bf16x8*)kr;
        bf16x8 b1 = *(const bf16x8*)(kr + 32);
        acc[jt] = __builtin_amdgcn_mfma_f32_16x16x32_bf16(a0, b0, acc[jt], 0, 0, 0);
        acc[jt] = __builtin_amdgcn_mfma_f32_16x16x32_bf16(a1, b1, acc[jt], 0, 0, 0);
    }

    // softmax (rows wave-private)
    const int ib = i0 + m0 + 4 * g;
    float mx[4] = {-1e30f, -1e30f, -1e30f, -1e30f};
    #pragma unroll
    for (int jt = 0; jt < 24; jt++) {
        float ra = radd_s[jt * 16 + l15];
        #pragma unroll
        for (int r = 0; r < 4; r++) {
            int idx = ME - (ib + r) + jt * 16 + l15;
            idx = (idx > 2 * ME - 2) ? (2 * ME - 2) : idx;
            float s = (acc[jt][r] + relp_s[idx] + ra) * inv_norm;
            acc[jt][r] = s;
            mx[r] = fmaxf(mx[r], s);
        }
    }
    #pragma unroll
    for (int r = 0; r < 4; r++)
        #pragma unroll
        for (int off = 1; off <= 8; off <<= 1)
            mx[r] = fmaxf(mx[r], __shfl_xor(mx[r], off));
    float sm[4] = {0.f, 0.f, 0.f, 0.f};
    #pragma unroll
    for (int jt = 0; jt < 24; jt++) {
        #pragma unroll
        for (int r = 0; r < 4; r++) {
            float e = __expf(acc[jt][r] - mx[r]);
            acc[jt][r] = e;
            sm[r] += e;
        }
    }
    #pragma unroll
    for (int r = 0; r < 4; r++) {
        #pragma unroll
        for (int off = 1; off <= 8; off <<= 1)
            sm[r] += __shfl_xor(sm[r], off);
        sm[r] = 1.0f / sm[r];
    }

    // two-pass PV (wave-private P rows; no barriers), V prefetch 1-ahead
    f32x4 oacc[4];
    #pragma unroll
    for (int dn = 0; dn < 4; dn++) oacc[dn] = f32x4{0.f, 0.f, 0.f, 0.f};
    #pragma unroll
    for (int half = 0; half < 2; half++) {
        #pragma unroll
        for (int jt = 0; jt < 12; jt++)
            #pragma unroll
            for (int r = 0; r < 4; r++)
                P[(m0 + 4 * g + r) * 200 + jt * 16 + l15] =
                    __float2bfloat16(acc[half * 12 + jt][r] * sm[r]);
        bf16x8 vreg[2][4];
        #pragma unroll
        for (int dn = 0; dn < 4; dn++)
            vreg[0][dn] = *(const bf16x8*)&vg[(size_t)(dn * 16 + l15) * LSEQ + half * 192 + 8 * g];
        #pragma unroll
        for (int jt2 = 0; jt2 < 6; jt2++) {
            const int s = jt2 & 1;
            if (jt2 < 5) {
                #pragma unroll
                for (int dn = 0; dn < 4; dn++)
                    vreg[s ^ 1][dn] = *(const bf16x8*)&vg[(size_t)(dn * 16 + l15) * LSEQ + half * 192 + (jt2 + 1) * 32 + 8 * g];
            }
            bf16x8 a = *(const bf16x8*)&P[(m0 + l15) * 200 + jt2 * 32 + 8 * g];
            #pragma unroll
            for (int dn = 0; dn < 4; dn++)
                oacc[dn] = __builtin_amdgcn_mfma_f32_16x16x32_bf16(a, vreg[s][dn], oacc[dn], 0, 0, 0);
        }
    }

    __syncthreads();   // all P reads done; reuse as O [i_loc][72]
    #pragma unroll
    for (int dn = 0; dn < 4; dn++)
        #pragma unroll
        for (int r = 0; r < 4; r++)
            O[(m0 + 4 * g + r) * 72 + dn * 16 + l15] = __float2bfloat16(oacc[dn][r]);
    __syncthreads();

    bf16* cg_ = ctxt + ((size_t)n * LSEQ + i0) * CHID + h * DH;
    #pragma unroll
    for (int t = 0; t < 2; t++) {
        int idx = t * 256 + tid;
        int ir = idx >> 3, u = idx & 7;
        *(uint4*)&cg_[(size_t)ir * CHID + u * 8] = *(const uint4*)&O[ir * 72 + u * 8];
    }
}

// ---------------------------------------------------------------------------
// Dense GEMM, 64x64 tiles, 768 blocks, fp32 out + bias.
// ---------------------------------------------------------------------------
__launch_bounds__(256, 6)
__global__ void dense_kernel(const bf16* __restrict__ Wb,
                             const bf16* __restrict__ Bt,
                             const float* __restrict__ bias,
                             float* __restrict__ outf)
{
    __shared__ __align__(16) float S[64 * 68];   // 17408 B
    const int tid = threadIdx.x;
    const int lane = tid & 63, w = tid >> 6;
    const int l15 = lane & 15, g = lane >> 4;
    const int Bid = blockIdx.x;
    const int rres = Bid & 7, qq = Bid >> 3;   // 0..95
    const int n = rres + 8 * (qq / 48);
    const int tt = qq % 48;
    const int o0 = (tt / 6) * 64;
    const int l0 = (tt % 6) * 64;

    const bf16* arow = Wb + (size_t)(o0 + l15) * CIO + 8 * g;
    const bf16* brow = Bt + ((size_t)n * LSEQ + l0 + w * 16 + l15) * CIO + 8 * g;

    f32x4 acc[4];
    #pragma unroll
    for (int mt = 0; mt < 4; mt++) acc[mt] = f32x4{0.f, 0.f, 0.f, 0.f};
    #pragma unroll 4
    for (int it = 0; it < 16; it++) {
        const int k0 = it * 32;
        bf16x8 b = *(const bf16x8*)&brow[k0];
        bf16x8 a[4];
        #pragma unroll
        for (int mt = 0; mt < 4; mt++)
            a[mt] = *(const bf16x8*)&arow[(size_t)mt * 16 * CIO + k0];
        #pragma unroll
        for (int mt = 0; mt < 4; mt++)
            acc[mt] = __builtin_amdgcn_mfma_f32_16x16x32_bf16(a[mt], b, acc[mt], 0, 0, 0);
    }

    #pragma unroll
    for (int mt = 0; mt < 4; mt++)
        #pragma unroll
        for (int r = 0; r < 4; r++)
            S[(mt * 16 + 4 * g + r) * 68 + w * 16 + l15] =
                acc[mt][r] + bias[o0 + mt * 16 + 4 * g + r];
    __syncthreads();
    float* og = outf + ((size_t)n * CHID + o0) * LSEQ + l0;
    #pragma unroll
    for (int t = 0; t < 4; t++) {
        int idx = t * 256 + tid;
        int orow = idx >> 4, u = idx & 15;
        *(float4*)&og[(size_t)orow * LSEQ + u * 4] = *(const float4*)&S[orow * 68 + u * 4];
    }
}

// ---------------------------------------------------------------------------
extern "C" void kernel_launch(void* const* d_in, const int* in_sizes, int n_in,
                              void* d_out, int out_size, void* d_ws, size_t ws_size,
                              hipStream_t stream)
{
    const float* x       = (const float*)d_in[0];
    const float* xorg    = (const float*)d_in[1];
    const float* abspos  = (const float*)d_in[2];
    const float* mask    = (const float*)d_in[3];
    const float* norm    = (const float*)d_in[4];
    const float* qkpos   = (const float*)d_in[5];
    const float* qkorg   = (const float*)d_in[6];
    const float* vorg    = (const float*)d_in[7];
    const float* relpos  = (const float*)d_in[8];
    const float* gate_w  = (const float*)d_in[9];
    const float* gate_b  = (const float*)d_in[10];
    const float* q_w     = (const float*)d_in[11];
    const float* k_w     = (const float*)d_in[12];
    const float* v_w     = (const float*)d_in[13];
    const float* dense_w = (const float*)d_in[14];
    const float* dense_b = (const float*)d_in[15];
    float* out = (float*)d_out;

    const size_t TEN = (size_t)N_B * CHID * LSEQ * sizeof(bf16);  // 6291456 B
    const size_t WB  = (size_t)CHID * CIO * sizeof(bf16);          // 524288 B
    char* ws = (char*)d_ws;
    bf16*  x1t  = (bf16*)(ws);                 // [n][l][c]; aliased by ctxt later
    bf16*  x0t  = (bf16*)(ws + TEN);
    bf16*  qb   = (bf16*)(ws + 2 * TEN);       // [n][h][i][d]
    bf16*  kb   = (bf16*)(ws + 3 * TEN);       // [n][h][j][d]
    bf16*  vb   = (bf16*)(ws + 4 * TEN);       // [n][c][l]
    bf16*  wqb  = (bf16*)(ws + 5 * TEN);
    bf16*  wkb  = (bf16*)(ws + 5 * TEN + WB);
    bf16*  wvb  = (bf16*)(ws + 5 * TEN + 2 * WB);
    bf16*  wdb  = (bf16*)(ws + 5 * TEN + 3 * WB);
    float* gpart = (float*)(ws + 5 * TEN + 4 * WB);
    bf16*  ctxt = x1t;   // x1t dead after qkv

    prep_kernel<<<dim3(CIO / 64, LSEQ / 64, N_B), 256, 0, stream>>>(
        x, xorg, abspos, qkorg, qkpos, vorg, gate_w,
        q_w, k_w, v_w, dense_w, wqb, wkb, wvb, wdb, x1t, x0t, gpart);
    qkv_kernel<<<1536, 256, 0, stream>>>(wqb, wkb, wvb, x1t, x0t, qb, kb, vb);
    attn_kernel<<<768, 256, 0, stream>>>(qb, kb, vb, gpart, gate_b,
                                         mask, norm, relpos, ctxt);
    dense_kernel<<<768, 256, 0, stream>>>(wdb, ctxt, dense_b, out);
}

// Round 12
// 198.732 us; speedup vs baseline: 1.3317x; 1.3317x over previous
//
#include <hip/hip_runtime.h>
#include <hip/hip_bf16.h>

#define N_B   16
#define CIO   512
#define LSEQ  384
#define DH    64
#define NH    8
#define CHID  512
#define ME    384

typedef __hip_bfloat16 bf16;
typedef __attribute__((ext_vector_type(8))) short bf16x8;
typedef __attribute__((ext_vector_type(4))) float f32x4;

#define AS1 __attribute__((address_space(1)))
#define AS3 __attribute__((address_space(3)))

__device__ __forceinline__ unsigned short f2bs(float f) {
    union { bf16 b; unsigned short u; } cv; cv.b = __float2bfloat16(f); return cv.u;
}

// async 16B global->LDS: lds dest = wave-uniform base + lane*16
__device__ __forceinline__ void gload_lds16(const bf16* g, bf16* l) {
    __builtin_amdgcn_global_load_lds((const AS1 unsigned int*)g,
                                     (AS3 unsigned int*)l, 16, 0, 0);
}

// ---------------------------------------------------------------------------
// prep (+ folded wconv): X1/X0 rezero -> bf16 transposed [n][l][c]; gate
// partials into gpart; first 512 flat-id blocks also convert weight chunks.
// ---------------------------------------------------------------------------
__launch_bounds__(256)
__global__ void prep_kernel(const float* __restrict__ x, const float* __restrict__ xorg,
                            const float* __restrict__ abspos,
                            const float* __restrict__ qkorg, const float* __restrict__ qkpos,
                            const float* __restrict__ vorg,
                            const float* __restrict__ gw,
                            const float* __restrict__ q_w, const float* __restrict__ k_w,
                            const float* __restrict__ v_w, const float* __restrict__ dense_w,
                            bf16* __restrict__ wqb, bf16* __restrict__ wkb,
                            bf16* __restrict__ wvb, bf16* __restrict__ wdb,
                            bf16* __restrict__ x1t, bf16* __restrict__ x0t,
                            float* __restrict__ gpart)
{
    __shared__ bf16 T1[64 * 72], T0[64 * 72];
    __shared__ float Traw[64 * 65];
    __shared__ float gws[NH * 64];
    __shared__ float r0[64], r1[64], r2[64];
    const int tid = threadIdx.x;
    const int cb = blockIdx.x;
    const int c0 = cb * 64;
    const int l0 = blockIdx.y * 64;
    const int n  = blockIdx.z;

    {
        int f = blockIdx.x + 8 * (blockIdx.y + 6 * blockIdx.z);
        if (f < 512) {
            int e = (f * 256 + tid) * 8;
            int which = e >> 18;
            int off = e & ((1 << 18) - 1);
            const float* s = which == 0 ? q_w : which == 1 ? k_w : which == 2 ? v_w : dense_w;
            bf16* d       = which == 0 ? wqb : which == 1 ? wkb : which == 2 ? wvb : wdb;
            float4 f0 = *(const float4*)&s[off];
            float4 f1 = *(const float4*)&s[off + 4];
            unsigned short u[8] = {f2bs(f0.x), f2bs(f0.y), f2bs(f0.z), f2bs(f0.w),
                                   f2bs(f1.x), f2bs(f1.y), f2bs(f1.z), f2bs(f1.w)};
            *(uint4*)&d[off] = *(uint4*)u;
        }
    }

    if (tid < 64) {
        int gidx = (c0 + tid) >> 3;
        r0[tid] = vorg[gidx];
        r1[tid] = qkorg[gidx];
        r2[tid] = qkpos[gidx];
    }
    for (int t = tid; t < NH * 64; t += 256) {
        int h = t >> 6, c = t & 63;
        gws[t] = gw[h * CIO + c0 + c];
    }
    __syncthreads();
    const int l = tid & 63, cs = tid >> 6;
    #pragma unroll
    for (int r = 0; r < 16; r++) {
        int cl = r * 4 + cs;
        size_t gi = ((size_t)n * CIO + c0 + cl) * LSEQ + l0 + l;
        float xv = x[gi], xo = xorg[gi];
        Traw[cl * 65 + l] = xv;
        T0[l * 72 + cl] = __float2bfloat16(xv + r0[cl] * xo);
        T1[l * 72 + cl] = __float2bfloat16(xv + r1[cl] * xo + r2[cl] * abspos[gi]);
    }
    __syncthreads();
    for (int t = tid; t < NH * 64; t += 256) {
        int h = t >> 6, ll = t & 63;
        float s = 0.f;
        #pragma unroll
        for (int c = 0; c < 64; c++) s += gws[h * 64 + c] * Traw[c * 65 + ll];
        gpart[(((size_t)cb * N_B + n) * NH + h) * LSEQ + l0 + ll] = s;
    }
    #pragma unroll
    for (int t = 0; t < 2; t++) {
        int idx = t * 256 + tid;
        int lr = idx >> 3, u = idx & 7;
        size_t go = ((size_t)n * LSEQ + l0 + lr) * CIO + c0 + u * 8;
        *(uint4*)&x1t[go] = *(const uint4*)&T1[lr * 72 + u * 8];
        *(uint4*)&x0t[go] = *(const uint4*)&T0[lr * 72 + u * 8];
    }
}

// ---------------------------------------------------------------------------
// Staged MFMA GEMM for q/k/v (m97 pattern): 128x128 tile, BK=32, LDS staging
// via global_load_lds(16B), 2-barrier K-loop, ds_read_b128 fragment feeds.
// wall = wq|wk|wv contiguous [1536][512]. Grid 576 = 12 ot x 3 lt x 16 n,
// n = Bid&7 (+8) for XCD L2 locality.
// ot 0..3: q (trans out), 4..7: k (trans out), 8..11: v (natural out).
// ---------------------------------------------------------------------------
__launch_bounds__(256)
__global__ void qkv_kernel(const bf16* __restrict__ wall,
                           const bf16* __restrict__ x1t, const bf16* __restrict__ x0t,
                           bf16* __restrict__ qb, bf16* __restrict__ kb,
                           bf16* __restrict__ vb)
{
    __shared__ __align__(16) char smem[17408];
    bf16* As = (bf16*)smem;            // [128][32]
    bf16* Bs = (bf16*)(smem + 8192);   // [128][32]
    bf16* S  = (bf16*)smem;            // epilogue [64][136]

    const int tid = threadIdx.x;
    const int lane = tid & 63, w = tid >> 6;
    const int l15 = lane & 15, g = lane >> 4;
    const int Bid = blockIdx.x;
    const int rres = Bid & 7, qq = Bid >> 3;    // 0..71
    const int n = rres + 8 * (qq / 36);
    const int t = qq % 36;
    const int ot = t / 3;          // 0..11
    const int lt = t % 3;
    const int osub = (w & 1) * 64, lsub = (w >> 1) * 64;

    const bf16* Wt = wall + (size_t)(ot * 128) * CIO;
    const bf16* Bt = (ot < 8 ? x1t : x0t) + ((size_t)n * LSEQ + lt * 128) * CIO;

    // staging coords: wave w stages segs {2w,2w+1} of A and of B.
    // seg*1024B, lane covers bytes [lane*16): elem e = seg*512 + lane*8
    const int segA = 2 * w, segB = 2 * w + 1;
    const int eA = segA * 512 + lane * 8;
    const int eB = segB * 512 + lane * 8;
    const int rA = eA >> 5, cA = eA & 31;
    const int rB = eB >> 5, cB = eB & 31;

    f32x4 acc[4][4];
    #pragma unroll
    for (int mt = 0; mt < 4; mt++)
        #pragma unroll
        for (int jt = 0; jt < 4; jt++) acc[mt][jt] = f32x4{0.f, 0.f, 0.f, 0.f};

    for (int it = 0; it < 16; ++it) {
        const int k0 = it * 32;
        gload_lds16(Wt + (size_t)rA * CIO + k0 + cA, As + segA * 512);
        gload_lds16(Wt + (size_t)rB * CIO + k0 + cB, As + segB * 512);
        gload_lds16(Bt + (size_t)rA * CIO + k0 + cA, Bs + segA * 512);
        gload_lds16(Bt + (size_t)rB * CIO + k0 + cB, Bs + segB * 512);
        __syncthreads();   // drains vmcnt (global_load_lds) before LDS reads
        bf16x8 af[4], bfv[4];
        #pragma unroll
        for (int mt = 0; mt < 4; mt++)
            af[mt] = *(const bf16x8*)&As[(osub + mt * 16 + l15) * 32 + 8 * g];
        #pragma unroll
        for (int jt = 0; jt < 4; jt++)
            bfv[jt] = *(const bf16x8*)&Bs[(lsub + jt * 16 + l15) * 32 + 8 * g];
        #pragma unroll
        for (int mt = 0; mt < 4; mt++)
            #pragma unroll
            for (int jt = 0; jt < 4; jt++)
                acc[mt][jt] = __builtin_amdgcn_mfma_f32_16x16x32_bf16(af[mt], bfv[jt], acc[mt][jt], 0, 0, 0);
        __syncthreads();   // protect LDS from next iter's staging
    }

    // lane holds C[o = osub+mt*16+4g+r][l = lsub+jt*16+l15]
    if (ot < 8) {
        // q/k: transposed out [n][h][l][d], h = 2*(ot&3) + (o>>6)
        bf16* dstb = (ot < 4) ? qb : kb;
        const int hbase = 2 * (ot & 3);
        #pragma unroll
        for (int lh = 0; lh < 2; ++lh) {
            if ((w >> 1) == lh) {
                #pragma unroll
                for (int mt = 0; mt < 4; mt++)
                    #pragma unroll
                    for (int jt = 0; jt < 4; jt++)
                        #pragma unroll
                        for (int r = 0; r < 4; r++)
                            S[(jt * 16 + l15) * 136 + osub + mt * 16 + 4 * g + r] =
                                __float2bfloat16(acc[mt][jt][r]);
            }
            __syncthreads();
            #pragma unroll
            for (int t2 = 0; t2 < 4; ++t2) {
                int idx = t2 * 256 + tid;          // 0..1023
                int lr = idx >> 4, u = idx & 15;
                int ho = u >> 3, dc = u & 7;
                bf16* dst = dstb + (((size_t)n * NH + hbase + ho) * LSEQ
                                    + lt * 128 + lh * 64 + lr) * DH + dc * 8;
                *(uint4*)dst = *(const uint4*)&S[lr * 136 + u * 8];
            }
            __syncthreads();
        }
    } else {
        // v: natural [n][o][l]
        const int ob = (ot - 8) * 128;
        #pragma unroll
        for (int oh = 0; oh < 2; ++oh) {
            if ((w & 1) == oh) {
                #pragma unroll
                for (int mt = 0; mt < 4; mt++)
                    #pragma unroll
                    for (int jt = 0; jt < 4; jt++)
                        #pragma unroll
                        for (int r = 0; r < 4; r++)
                            S[(mt * 16 + 4 * g + r) * 136 + lsub + jt * 16 + l15] =
                                __float2bfloat16(acc[mt][jt][r]);
            }
            __syncthreads();
            #pragma unroll
            for (int t2 = 0; t2 < 4; ++t2) {
                int idx = t2 * 256 + tid;
                int orr = idx >> 4, u = idx & 15;
                bf16* dst = vb + ((size_t)(n * CHID + ob + oh * 64 + orr)) * LSEQ
                               + lt * 128 + u * 8;
                *(uint4*)dst = *(const uint4*)&S[orr * 136 + u * 8];
            }
            __syncthreads();
        }
    }
}

// ---------------------------------------------------------------------------
// MFMA attention: 768 blocks, n = Bid&7 (+8). Direct-global K B-frags,
// two-pass PV through P[64][200], V prefetch.
// ---------------------------------------------------------------------------
__launch_bounds__(256, 3)
__global__ void attn_kernel(const bf16* __restrict__ qt,
                            const bf16* __restrict__ kt,
                            const bf16* __restrict__ v,
                            const float* __restrict__ gpart,
                            const float* __restrict__ gb,
                            const float* __restrict__ mask,
                            const float* __restrict__ norm,
                            const float* __restrict__ relpos,
                            bf16* __restrict__ ctxt)
{
    __shared__ __align__(16) char smem[25600];
    __shared__ float relp_s[2 * ME - 1];
    __shared__ float radd_s[LSEQ];

    bf16* P = (bf16*)smem;
    bf16* O = (bf16*)smem;

    const int tid = threadIdx.x;
    const int Bid = blockIdx.x;
    const int rres = Bid & 7, qq = Bid >> 3;
    const int n = rres + 8 * (qq / 48);
    const int rem = qq % 48;
    const int h = rem / 6;
    const int i0 = (rem % 6) * 64;
    const int lane = tid & 63;
    const int w = tid >> 6;
    const int l15 = lane & 15, g = lane >> 4;
    const int m0 = w * 16;

    const size_t nh = (size_t)n * NH + h;
    const bf16* kt_g = kt + nh * LSEQ * DH;
    const bf16* vg   = v + ((size_t)n * CHID + h * DH) * LSEQ;

    {
        const float gbh = gb[h];
        for (int i = tid; i < LSEQ; i += 256) {
            float s = gbh + mask[(size_t)n * LSEQ + i];
            #pragma unroll
            for (int cb = 0; cb < 8; cb++)
                s += gpart[(((size_t)cb * N_B + n) * NH + h) * LSEQ + i];
            radd_s[i] = s;
        }
    }
    for (int i = tid; i < 2 * ME - 1; i += 256) relp_s[i] = relpos[i];

    const bf16* qrow = qt + (nh * LSEQ + i0 + m0 + l15) * DH;
    bf16x8 a0 = *(const bf16x8*)&qrow[8 * g];
    bf16x8 a1 = *(const bf16x8*)&qrow[8 * g + 32];
    const float inv_norm = 1.0f / norm[n];
    __syncthreads();

    f32x4 acc[24];
    #pragma unroll
    for (int jt = 0; jt < 24; jt++) acc[jt] = f32x4{0.f, 0.f, 0.f, 0.f};
    #pragma unroll
    for (int jt = 0; jt < 24; jt++) {
        const bf16* kr = &kt_g[(size_t)(jt * 16 + l15) * DH + 8 * g];
        bf16x8 b0 = *(const bf16x8*)kr;
        bf16x8 b1 = *(const bf16x8*)(kr + 32);
        acc[jt] = __builtin_amdgcn_mfma_f32_16x16x32_bf16(a0, b0, acc[jt], 0, 0, 0);
        acc[jt] = __builtin_amdgcn_mfma_f32_16x16x32_bf16(a1, b1, acc[jt], 0, 0, 0);
    }

    const int ib = i0 + m0 + 4 * g;
    float mx[4] = {-1e30f, -1e30f, -1e30f, -1e30f};
    #pragma unroll
    for (int jt = 0; jt < 24; jt++) {
        float ra = radd_s[jt * 16 + l15];
        #pragma unroll
        for (int r = 0; r < 4; r++) {
            int idx = ME - (ib + r) + jt * 16 + l15;
            idx = (idx > 2 * ME - 2) ? (2 * ME - 2) : idx;
            float s = (acc[jt][r] + relp_s[idx] + ra) * inv_norm;
            acc[jt][r] = s;
            mx[r] = fmaxf(mx[r], s);
        }
    }
    #pragma unroll
    for (int r = 0; r < 4; r++)
        #pragma unroll
        for (int off = 1; off <= 8; off <<= 1)
            mx[r] = fmaxf(mx[r], __shfl_xor(mx[r], off));
    float sm[4] = {0.f, 0.f, 0.f, 0.f};
    #pragma unroll
    for (int jt = 0; jt < 24; jt++) {
        #pragma unroll
        for (int r = 0; r < 4; r++) {
            float e = __expf(acc[jt][r] - mx[r]);
            acc[jt][r] = e;
            sm[r] += e;
        }
    }
    #pragma unroll
    for (int r = 0; r < 4; r++) {
        #pragma unroll
        for (int off = 1; off <= 8; off <<= 1)
            sm[r] += __shfl_xor(sm[r], off);
        sm[r] = 1.0f / sm[r];
    }

    f32x4 oacc[4];
    #pragma unroll
    for (int dn = 0; dn < 4; dn++) oacc[dn] = f32x4{0.f, 0.f, 0.f, 0.f};
    #pragma unroll
    for (int half = 0; half < 2; half++) {
        #pragma unroll
        for (int jt = 0; jt < 12; jt++)
            #pragma unroll
            for (int r = 0; r < 4; r++)
                P[(m0 + 4 * g + r) * 200 + jt * 16 + l15] =
                    __float2bfloat16(acc[half * 12 + jt][r] * sm[r]);
        bf16x8 vreg[2][4];
        #pragma unroll
        for (int dn = 0; dn < 4; dn++)
            vreg[0][dn] = *(const bf16x8*)&vg[(size_t)(dn * 16 + l15) * LSEQ + half * 192 + 8 * g];
        #pragma unroll
        for (int jt2 = 0; jt2 < 6; jt2++) {
            const int s = jt2 & 1;
            if (jt2 < 5) {
                #pragma unroll
                for (int dn = 0; dn < 4; dn++)
                    vreg[s ^ 1][dn] = *(const bf16x8*)&vg[(size_t)(dn * 16 + l15) * LSEQ + half * 192 + (jt2 + 1) * 32 + 8 * g];
            }
            bf16x8 a = *(const bf16x8*)&P[(m0 + l15) * 200 + jt2 * 32 + 8 * g];
            #pragma unroll
            for (int dn = 0; dn < 4; dn++)
                oacc[dn] = __builtin_amdgcn_mfma_f32_16x16x32_bf16(a, vreg[s][dn], oacc[dn], 0, 0, 0);
        }
    }

    __syncthreads();
    #pragma unroll
    for (int dn = 0; dn < 4; dn++)
        #pragma unroll
        for (int r = 0; r < 4; r++)
            O[(m0 + 4 * g + r) * 72 + dn * 16 + l15] = __float2bfloat16(oacc[dn][r]);
    __syncthreads();

    bf16* cg_ = ctxt + ((size_t)n * LSEQ + i0) * CHID + h * DH;
    #pragma unroll
    for (int t = 0; t < 2; t++) {
        int idx = t * 256 + tid;
        int ir = idx >> 3, u = idx & 7;
        *(uint4*)&cg_[(size_t)ir * CHID + u * 8] = *(const uint4*)&O[ir * 72 + u * 8];
    }
}

// ---------------------------------------------------------------------------
// Dense GEMM, 64x64 tiles, 768 blocks, fp32 out + bias.
// ---------------------------------------------------------------------------
__launch_bounds__(256, 6)
__global__ void dense_kernel(const bf16* __restrict__ Wb,
                             const bf16* __restrict__ Bt,
                             const float* __restrict__ bias,
                             float* __restrict__ outf)
{
    __shared__ __align__(16) float S[64 * 68];
    const int tid = threadIdx.x;
    const int lane = tid & 63, w = tid >> 6;
    const int l15 = lane & 15, g = lane >> 4;
    const int Bid = blockIdx.x;
    const int rres = Bid & 7, qq = Bid >> 3;
    const int n = rres + 8 * (qq / 48);
    const int tt = qq % 48;
    const int o0 = (tt / 6) * 64;
    const int l0 = (tt % 6) * 64;

    const bf16* arow = Wb + (size_t)(o0 + l15) * CIO + 8 * g;
    const bf16* brow = Bt + ((size_t)n * LSEQ + l0 + w * 16 + l15) * CIO + 8 * g;

    f32x4 acc[4];
    #pragma unroll
    for (int mt = 0; mt < 4; mt++) acc[mt] = f32x4{0.f, 0.f, 0.f, 0.f};
    #pragma unroll 4
    for (int it = 0; it < 16; it++) {
        const int k0 = it * 32;
        bf16x8 b = *(const bf16x8*)&brow[k0];
        bf16x8 a[4];
        #pragma unroll
        for (int mt = 0; mt < 4; mt++)
            a[mt] = *(const bf16x8*)&arow[(size_t)mt * 16 * CIO + k0];
        #pragma unroll
        for (int mt = 0; mt < 4; mt++)
            acc[mt] = __builtin_amdgcn_mfma_f32_16x16x32_bf16(a[mt], b, acc[mt], 0, 0, 0);
    }

    #pragma unroll
    for (int mt = 0; mt < 4; mt++)
        #pragma unroll
        for (int r = 0; r < 4; r++)
            S[(mt * 16 + 4 * g + r) * 68 + w * 16 + l15] =
                acc[mt][r] + bias[o0 + mt * 16 + 4 * g + r];
    __syncthreads();
    float* og = outf + ((size_t)n * CHID + o0) * LSEQ + l0;
    #pragma unroll
    for (int t = 0; t < 4; t++) {
        int idx = t * 256 + tid;
        int orow = idx >> 4, u = idx & 15;
        *(float4*)&og[(size_t)orow * LSEQ + u * 4] = *(const float4*)&S[orow * 68 + u * 4];
    }
}

// ---------------------------------------------------------------------------
extern "C" void kernel_launch(void* const* d_in, const int* in_sizes, int n_in,
                              void* d_out, int out_size, void* d_ws, size_t ws_size,
                              hipStream_t stream)
{
    const float* x       = (const float*)d_in[0];
    const float* xorg    = (const float*)d_in[1];
    const float* abspos  = (const float*)d_in[2];
    const float* mask    = (const float*)d_in[3];
    const float* norm    = (const float*)d_in[4];
    const float* qkpos   = (const float*)d_in[5];
    const float* qkorg   = (const float*)d_in[6];
    const float* vorg    = (const float*)d_in[7];
    const float* relpos  = (const float*)d_in[8];
    const float* gate_w  = (const float*)d_in[9];
    const float* gate_b  = (const float*)d_in[10];
    const float* q_w     = (const float*)d_in[11];
    const float* k_w     = (const float*)d_in[12];
    const float* v_w     = (const float*)d_in[13];
    const float* dense_w = (const float*)d_in[14];
    const float* dense_b = (const float*)d_in[15];
    float* out = (float*)d_out;

    const size_t TEN = (size_t)N_B * CHID * LSEQ * sizeof(bf16);  // 6291456 B
    const size_t WB  = (size_t)CHID * CIO * sizeof(bf16);          // 524288 B
    char* ws = (char*)d_ws;
    bf16*  x1t  = (bf16*)(ws);
    bf16*  x0t  = (bf16*)(ws + TEN);
    bf16*  qb   = (bf16*)(ws + 2 * TEN);
    bf16*  kb   = (bf16*)(ws + 3 * TEN);
    bf16*  vb   = (bf16*)(ws + 4 * TEN);
    bf16*  wqb  = (bf16*)(ws + 5 * TEN);              // wq|wk|wv|wd contiguous
    bf16*  wkb  = (bf16*)(ws + 5 * TEN + WB);
    bf16*  wvb  = (bf16*)(ws + 5 * TEN + 2 * WB);
    bf16*  wdb  = (bf16*)(ws + 5 * TEN + 3 * WB);
    float* gpart = (float*)(ws + 5 * TEN + 4 * WB);
    bf16*  ctxt = x1t;   // x1t dead after qkv

    prep_kernel<<<dim3(CIO / 64, LSEQ / 64, N_B), 256, 0, stream>>>(
        x, xorg, abspos, qkorg, qkpos, vorg, gate_w,
        q_w, k_w, v_w, dense_w, wqb, wkb, wvb, wdb, x1t, x0t, gpart);
    qkv_kernel<<<576, 256, 0, stream>>>(wqb, x1t, x0t, qb, kb, vb);
    attn_kernel<<<768, 256, 0, stream>>>(qb, kb, vb, gpart, gate_b,
                                         mask, norm, relpos, ctxt);
    dense_kernel<<<768, 256, 0, stream>>>(wdb, ctxt, dense_b, out);
}